// Round 5
// baseline (147.747 us; speedup 1.0000x reference)
//
#include <hip/hip_runtime.h>

// pyramid_roi_align (Mask R-CNN), MI355X.
// R5: persistent blocks, SINGLE-buffered LDS table, plain stores.
// (R4's nontemporal stores caused post-timing divergence under the 0xAA
// poison-replay protocol — dirty-L2-line clobber suspected; dbuf removed too
// to isolate. Keep: persistent 2048-block grid, R3 float2 paired-column
// gathers, 49-cell LDS interp table, incremental c/p index math.)

#define POOL 7
#define ELEMS_PER_BOX (256 * 49)             // 12544
#define CHUNKS 7
#define CHUNK_ELEMS (ELEMS_PER_BOX / CHUNKS) // 1792
#define GRID 2048

typedef float f2 __attribute__((ext_vector_type(2)));

__global__ __launch_bounds__(256, 8) void roi_align_kernel(
    const float* __restrict__ boxes,
    const float* __restrict__ p2, const float* __restrict__ p3,
    const float* __restrict__ p4, const float* __restrict__ p5,
    float* __restrict__ out, int N)
{
    __shared__ int   s_off0[49], s_off1[49];
    __shared__ float s_a[49], s_b[49], s_w0[49], s_w1[49];
    __shared__ const float* s_fmap;
    __shared__ int   s_HW;

    const int tid = threadIdx.x;
    const int nwi = N * CHUNKS;

    for (int wi = blockIdx.x; wi < nwi; wi += GRID) {
        const int n     = wi % N;
        const int chunk = wi / N;

        if (tid < 49) {
            const float by1 = boxes[4 * n + 0];
            const float bx1 = boxes[4 * n + 1];
            const float by2 = boxes[4 * n + 2];
            const float bx2 = boxes[4 * n + 3];
            const float h = by2 - by1;
            const float w = bx2 - bx1;
            // roi_level = clip(round(4 + log2(sqrt(h*w)/(224/1024))), 2, 5)
            float rl = 4.0f + log2f(sqrtf(h * w) / 0.21875f);
            int level = (int)rintf(rl);        // half-even = jnp.round
            level = min(5, max(2, level));
            const int H = 256 >> (level - 2);
            const int W = H;
            if (tid == 0) {
                s_HW = H * W;
                s_fmap = (level == 2) ? p2 : (level == 3) ? p3 :
                         (level == 4) ? p4 : p5;
            }
            const int py = tid / 7;
            const int px = tid - 7 * py;

            const float ty = (float)py * (1.0f / 6.0f);
            const float ys = (by1 + ty * (by2 - by1)) * (float)(H - 1);
            const float yf = floorf(ys);
            const float ly = ys - yf;
            int y0 = (int)yf; y0 = min(H - 1, max(0, y0));
            const int y1 = min(H - 1, y0 + 1);
            const float vy = (ys >= 0.0f && ys <= (float)(H - 1)) ? 1.0f : 0.0f;

            const float tx = (float)px * (1.0f / 6.0f);
            const float xs = (bx1 + tx * (bx2 - bx1)) * (float)(W - 1);
            const float xf = floorf(xs);
            const float lx = xs - xf;
            int x0 = (int)xf; x0 = min(W - 1, max(0, x0));
            const float vx = (xs >= 0.0f && xs <= (float)(W - 1)) ? 1.0f : 0.0f;

            const int xb = min(x0, W - 2);     // float2 base column
            const bool edge = (x0 != xb);      // x0==W-1: q.y holds f[x0]=f[x1]
            s_off0[tid] = y0 * W + xb;
            s_off1[tid] = y1 * W + xb;
            s_a[tid]  = edge ? 0.0f : vx * (1.0f - lx);
            s_b[tid]  = edge ? vx : vx * lx;
            s_w0[tid] = vy * (1.0f - ly);
            s_w1[tid] = vy * ly;
        }
        __syncthreads();

        const float* __restrict__ fmap = s_fmap;
        const int HW = s_HW;

        const int i0 = chunk * CHUNK_ELEMS + tid;
        int cc = i0 / 49;
        int p  = i0 - cc * 49;

        // Phase 1: issue all 14 float2 gathers before any use
        f2  q0[CHUNKS], q1[CHUNKS];
        int cell[CHUNKS];
#pragma unroll
        for (int k = 0; k < CHUNKS; ++k) {
            cell[k] = p;
            const float* plane = fmap + (size_t)cc * HW;
            q0[k] = *(const f2*)(plane + s_off0[p]);
            q1[k] = *(const f2*)(plane + s_off1[p]);
            cc += 5; p += 11;                  // advance 256 elems: 256 = 5*49+11
            if (p >= 49) { p -= 49; cc += 1; }
        }

        // Phase 2: combine + coalesced store
        float* __restrict__ obase = out + (size_t)n * ELEMS_PER_BOX
                                        + chunk * CHUNK_ELEMS;
#pragma unroll
        for (int k = 0; k < CHUNKS; ++k) {
            const int pc = cell[k];
            const float a = s_a[pc], b = s_b[pc];
            const float r0 = q0[k].x * a + q0[k].y * b;
            const float r1 = q1[k].x * a + q1[k].y * b;
            obase[tid + k * 256] = r0 * s_w0[pc] + r1 * s_w1[pc];
        }
        __syncthreads();   // protect table before next iteration's setup
    }
}

extern "C" void kernel_launch(void* const* d_in, const int* in_sizes, int n_in,
                              void* d_out, int out_size, void* d_ws, size_t ws_size,
                              hipStream_t stream) {
    const float* boxes = (const float*)d_in[0];
    const float* p2    = (const float*)d_in[1];
    const float* p3    = (const float*)d_in[2];
    const float* p4    = (const float*)d_in[3];
    const float* p5    = (const float*)d_in[4];
    float* out = (float*)d_out;
    const int N = in_sizes[0] / 4;

    const int nwi  = N * CHUNKS;
    const int grid = (nwi < GRID) ? nwi : GRID;
    roi_align_kernel<<<grid, 256, 0, stream>>>(boxes, p2, p3, p4, p5, out, N);
}

// Round 6
// 146.462 us; speedup vs baseline: 1.0088x; 1.0088x over previous
//
#include <hip/hip_runtime.h>

// pyramid_roi_align (Mask R-CNN), MI355X.
// R6: cut LDS + address overhead in the hot loop.
//  - Per-cell tables packed: int2 {off0,off1} (ds_read_b64) and
//    float4 {a,b,w0,w1} (ds_read_b128): 2 LDS insts/cell instead of 6.
//  - Plane pointer + HW made wave-uniform via readfirstlane; gather addresses
//    are 32-bit BYTE offsets off an SGPR base (saddr+voffset form, no per-lane
//    64-bit address chain).
//  - Keep: persistent 2048-block grid, R3 float2 paired-column gathers,
//    single-buffered table, plain coalesced stores.

#define POOL 7
#define ELEMS_PER_BOX (256 * 49)             // 12544
#define CHUNKS 7
#define CHUNK_ELEMS (ELEMS_PER_BOX / CHUNKS) // 1792
#define GRID 2048

typedef float f2 __attribute__((ext_vector_type(2)));
typedef float f4 __attribute__((ext_vector_type(4)));
typedef int   i2 __attribute__((ext_vector_type(2)));

__device__ __forceinline__ const char* uniform_ptr(const float* p) {
    uint64_t u = (uint64_t)p;
    uint32_t lo = __builtin_amdgcn_readfirstlane((uint32_t)u);
    uint32_t hi = __builtin_amdgcn_readfirstlane((uint32_t)(u >> 32));
    return (const char*)(((uint64_t)hi << 32) | lo);
}

__global__ __launch_bounds__(256, 8) void roi_align_kernel(
    const float* __restrict__ boxes,
    const float* __restrict__ p2, const float* __restrict__ p3,
    const float* __restrict__ p4, const float* __restrict__ p5,
    float* __restrict__ out, int N)
{
    __shared__ i2  s_off[49];     // {off0, off1} (element offsets in plane)
    __shared__ f4  s_wt[49];      // {a, b, w0, w1}
    __shared__ const float* s_fmap;
    __shared__ int s_HW;

    const int tid = threadIdx.x;
    const int nwi = N * CHUNKS;

    for (int wi = blockIdx.x; wi < nwi; wi += GRID) {
        const int n     = wi % N;
        const int chunk = wi / N;

        if (tid < 49) {
            const float by1 = boxes[4 * n + 0];
            const float bx1 = boxes[4 * n + 1];
            const float by2 = boxes[4 * n + 2];
            const float bx2 = boxes[4 * n + 3];
            const float h = by2 - by1;
            const float w = bx2 - bx1;
            // roi_level = clip(round(4 + log2(sqrt(h*w)/(224/1024))), 2, 5)
            float rl = 4.0f + log2f(sqrtf(h * w) / 0.21875f);
            int level = (int)rintf(rl);        // half-even = jnp.round
            level = min(5, max(2, level));
            const int H = 256 >> (level - 2);
            const int W = H;
            if (tid == 0) {
                s_HW = H * W;
                s_fmap = (level == 2) ? p2 : (level == 3) ? p3 :
                         (level == 4) ? p4 : p5;
            }
            const int py = tid / 7;
            const int px = tid - 7 * py;

            const float ty = (float)py * (1.0f / 6.0f);
            const float ys = (by1 + ty * (by2 - by1)) * (float)(H - 1);
            const float yf = floorf(ys);
            const float ly = ys - yf;
            int y0 = (int)yf; y0 = min(H - 1, max(0, y0));
            const int y1 = min(H - 1, y0 + 1);
            const float vy = (ys >= 0.0f && ys <= (float)(H - 1)) ? 1.0f : 0.0f;

            const float tx = (float)px * (1.0f / 6.0f);
            const float xs = (bx1 + tx * (bx2 - bx1)) * (float)(W - 1);
            const float xf = floorf(xs);
            const float lx = xs - xf;
            int x0 = (int)xf; x0 = min(W - 1, max(0, x0));
            const float vx = (xs >= 0.0f && xs <= (float)(W - 1)) ? 1.0f : 0.0f;

            const int xb = min(x0, W - 2);     // float2 base column
            const bool edge = (x0 != xb);      // x0==W-1: q.y holds f[x0]=f[x1]
            i2 off; off.x = y0 * W + xb; off.y = y1 * W + xb;
            f4 wt;
            wt.x = edge ? 0.0f : vx * (1.0f - lx);   // a
            wt.y = edge ? vx : vx * lx;              // b
            wt.z = vy * (1.0f - ly);                 // w0
            wt.w = vy * ly;                          // w1
            s_off[tid] = off;
            s_wt[tid]  = wt;
        }
        __syncthreads();

        const char* __restrict__ base = uniform_ptr(s_fmap);   // SGPR base
        const int HW = __builtin_amdgcn_readfirstlane(s_HW);

        const int i0 = chunk * CHUNK_ELEMS + tid;
        int cc = i0 / 49;
        int p  = i0 - cc * 49;
        unsigned int pbase = (unsigned int)(cc * HW) * 4u;     // byte offset of plane
        const unsigned int stepHW  = (unsigned int)HW * 20u;   // 5 planes in bytes
        const unsigned int stepHW1 = (unsigned int)HW * 4u;

        // Phase 1: issue all 14 float2 gathers (saddr + 32-bit byte voffset)
        f2  q0[CHUNKS], q1[CHUNKS];
        int cell[CHUNKS];
#pragma unroll
        for (int k = 0; k < CHUNKS; ++k) {
            cell[k] = p;
            const i2 off = s_off[p];
            q0[k] = *(const f2*)(base + (pbase + (unsigned int)off.x * 4u));
            q1[k] = *(const f2*)(base + (pbase + (unsigned int)off.y * 4u));
            pbase += stepHW; p += 11;          // advance 256 elems: 256 = 5*49+11
            if (p >= 49) { p -= 49; pbase += stepHW1; }
        }

        // Phase 2: weights via one ds_read_b128 per cell, combine, store
        float* __restrict__ obase = out + (size_t)n * ELEMS_PER_BOX
                                        + chunk * CHUNK_ELEMS;
#pragma unroll
        for (int k = 0; k < CHUNKS; ++k) {
            const f4 wt = s_wt[cell[k]];
            const float r0 = q0[k].x * wt.x + q0[k].y * wt.y;
            const float r1 = q1[k].x * wt.x + q1[k].y * wt.y;
            obase[tid + k * 256] = r0 * wt.z + r1 * wt.w;
        }
        __syncthreads();   // protect table before next iteration's setup
    }
}

extern "C" void kernel_launch(void* const* d_in, const int* in_sizes, int n_in,
                              void* d_out, int out_size, void* d_ws, size_t ws_size,
                              hipStream_t stream) {
    const float* boxes = (const float*)d_in[0];
    const float* p2    = (const float*)d_in[1];
    const float* p3    = (const float*)d_in[2];
    const float* p4    = (const float*)d_in[3];
    const float* p5    = (const float*)d_in[4];
    float* out = (float*)d_out;
    const int N = in_sizes[0] / 4;

    const int nwi  = N * CHUNKS;
    const int grid = (nwi < GRID) ? nwi : GRID;
    roi_align_kernel<<<grid, 256, 0, stream>>>(boxes, p2, p3, p4, p5, out, N);
}